// Round 1
// baseline (539.609 us; speedup 1.0000x reference)
//
#include <hip/hip_runtime.h>
#include <hip/hip_bf16.h>

#define MN 16384
#define SPLITS 4
#define KSLICE (MN / SPLITS)     // 4096
#define BK 64
#define NSTEPS (KSLICE / BK)     // 64

typedef float f32x4 __attribute__((ext_vector_type(4)));
typedef short s16x8 __attribute__((ext_vector_type(8)));
typedef unsigned short u16x8 __attribute__((ext_vector_type(8)));
typedef unsigned short u16;

__device__ __forceinline__ u16 f2bf(float f) {
  unsigned u = __builtin_bit_cast(unsigned, f);
  u += 0x7FFFu + ((u >> 16) & 1u);   // round-to-nearest-even
  return (u16)(u >> 16);
}

__device__ __forceinline__ void async16(void* lds, const void* g) {
  __builtin_amdgcn_global_load_lds(
      (const __attribute__((address_space(1))) unsigned int*)g,
      (__attribute__((address_space(3))) unsigned int*)lds, 16, 0, 0);
}

// ---------------------------------------------------------------------------
// K1: support1 = x @ W2, written as bf16 in MFMA-fragment order:
//     B1[( (k>>3)*128 + col )*8 + (k&7)]  (k = row index of support1)
// ---------------------------------------------------------------------------
__global__ __launch_bounds__(256)
void k1_xw2(const float* __restrict__ x, const float* __restrict__ W2,
            u16* __restrict__ B1) {
  __shared__ __align__(16) float xs[64 * 128];
  const int t = threadIdx.x;
  const long rowbase = (long)blockIdx.x * 64;
  const f32x4* xg = (const f32x4*)(x + rowbase * 128);
  f32x4* xl = (f32x4*)xs;
#pragma unroll
  for (int i = 0; i < 8; ++i) xl[t + 256 * i] = xg[t + 256 * i];
  __syncthreads();
  const int r0 = (t >> 5) * 8;   // 8 rows per thread (8-aligned)
  const int c0 = (t & 31) * 4;   // 4 cols per thread
  float acc[8][4] = {};
  for (int k = 0; k < 128; k += 4) {
    f32x4 w[4];
#pragma unroll
    for (int kk = 0; kk < 4; ++kk) w[kk] = *(const f32x4*)(W2 + (k + kk) * 128 + c0);
#pragma unroll
    for (int i = 0; i < 8; ++i) {
      f32x4 xv = *(const f32x4*)(xs + (r0 + i) * 128 + k);
#pragma unroll
      for (int kk = 0; kk < 4; ++kk)
#pragma unroll
        for (int j = 0; j < 4; ++j) acc[i][j] += xv[kk] * w[kk][j];
    }
  }
  const long R8 = (rowbase + r0) >> 3;
#pragma unroll
  for (int j = 0; j < 4; ++j) {
    u16x8 v;
#pragma unroll
    for (int i = 0; i < 8; ++i) v[i] = f2bf(acc[i][j]);
    *(u16x8*)(B1 + (R8 * 128 + (c0 + j)) * 8) = v;
  }
}

// ---------------------------------------------------------------------------
// Big kernel: P[s] = adj[:, k-slice s] @ B  (B in bf16 fragment order).
// 512 threads = 8 waves; each wave owns a 16-row stripe of a 128-row tile,
// full N=128 via 8 col-tiles of mfma_f32_16x16x32_bf16. Split-K = 4.
// A loaded per-lane from global f32 (nontemporal), cvt to bf16 in-register.
// B double-buffered in LDS via global_load_lds (linear copy).
// ---------------------------------------------------------------------------
__global__ __launch_bounds__(512, 4)
void big_mm(const float* __restrict__ A, const u16* __restrict__ Bswz,
            float* __restrict__ P) {
  __shared__ __align__(16) u16 Bs[2][8192];   // 2 x 16 KB (BK=64 x 128 bf16)
  const int tid  = threadIdx.x;
  const int wid  = tid >> 6;
  const int lane = tid & 63;
  const int g    = lane >> 4;    // k-group
  const int cl   = lane & 15;    // A-row / B-col / C-col within tile
  const int tile_m = blockIdx.x & 127;
  const int s      = blockIdx.x >> 7;
  const long k0 = (long)s * KSLICE;

  const char* bsrc = (const char*)Bswz + k0 * 256 + (long)tid * 16;
  const float* aptr = A + (long)(tile_m * 128 + wid * 16 + cl) * MN + k0 + 8 * g;

  f32x4 acc[8] = {};

  // prologue: stage step 0 into buffer 0
  {
    u16* d0 = &Bs[0][0] + wid * 512;
    async16(d0, bsrc);
    async16(d0 + 4096, bsrc + 8192);
  }
  asm volatile("s_waitcnt vmcnt(0)" ::: "memory");
  __builtin_amdgcn_s_barrier();

  for (int t = 0; t < NSTEPS; ++t) {
    const float* ap = aptr + t * BK;
    f32x4 a0 = __builtin_nontemporal_load((const f32x4*)ap);
    f32x4 a1 = __builtin_nontemporal_load((const f32x4*)(ap + 4));
    f32x4 a2 = __builtin_nontemporal_load((const f32x4*)(ap + 32));
    f32x4 a3 = __builtin_nontemporal_load((const f32x4*)(ap + 36));
    if (t + 1 < NSTEPS) {  // stage next tile; stays in flight through compute
      u16* d = &Bs[(t + 1) & 1][0] + wid * 512;
      const char* src = bsrc + (long)(t + 1) * 16384;
      async16(d, src);
      async16(d + 4096, src + 8192);
    }
    s16x8 af0, af1;
#pragma unroll
    for (int j = 0; j < 4; ++j) {
      af0[j]     = (short)f2bf(a0[j]);
      af0[4 + j] = (short)f2bf(a1[j]);
      af1[j]     = (short)f2bf(a2[j]);
      af1[4 + j] = (short)f2bf(a3[j]);
    }
    const u16x8* bb = (const u16x8*)&Bs[t & 1][0];
#pragma unroll
    for (int c = 0; c < 8; ++c) {
      u16x8 b0 = bb[g * 128 + 16 * c + cl];
      u16x8 b1 = bb[512 + g * 128 + 16 * c + cl];
      acc[c] = __builtin_amdgcn_mfma_f32_16x16x32_bf16(
          af0, __builtin_bit_cast(s16x8, b0), acc[c], 0, 0, 0);
      acc[c] = __builtin_amdgcn_mfma_f32_16x16x32_bf16(
          af1, __builtin_bit_cast(s16x8, b1), acc[c], 0, 0, 0);
    }
    // publish next buffer: own stage + ds_reads complete, then block barrier
    asm volatile("s_waitcnt vmcnt(0) lgkmcnt(0)" ::: "memory");
    __builtin_amdgcn_s_barrier();
  }

  // C/D layout (HW-verified): col = lane&15, row = 4*(lane>>4) + reg
  float* pb = P + ((long)s * MN + tile_m * 128 + wid * 16) * 128;
#pragma unroll
  for (int c = 0; c < 8; ++c)
#pragma unroll
    for (int q = 0; q < 4; ++q)
      __builtin_nontemporal_store(acc[c][q], &pb[(g * 4 + q) * 128 + 16 * c + cl]);
}

// ---------------------------------------------------------------------------
// K3: LH = sum_s P[s] + b2 (tile in LDS); then
//     B2 = bf16frag(LH @ W4);  R = LH @ res_w^T + res_b + b4
// ---------------------------------------------------------------------------
__global__ __launch_bounds__(256)
void k3_mid(const float* __restrict__ P, const float* __restrict__ b2,
            const float* __restrict__ W4, const float* __restrict__ res_w,
            const float* __restrict__ b4, const float* __restrict__ res_b,
            u16* __restrict__ B2, float* __restrict__ Rr) {
  __shared__ __align__(16) float hs[64 * 128];
  const int t = threadIdx.x;
  const long rowbase = (long)blockIdx.x * 64;
  const long base = rowbase * 32;            // f32x4 units (128/4 per row)
  const f32x4* P0 = (const f32x4*)P + base;
  const f32x4* P1 = (const f32x4*)P + (long)MN * 32 + base;
  const f32x4* P2 = (const f32x4*)P + 2L * MN * 32 + base;
  const f32x4* P3 = (const f32x4*)P + 3L * MN * 32 + base;
  const f32x4* b2v = (const f32x4*)b2;
  f32x4* hl = (f32x4*)hs;
#pragma unroll
  for (int i = 0; i < 8; ++i) {
    int idx = t + 256 * i;
    f32x4 v = __builtin_nontemporal_load(P0 + idx);
    v += __builtin_nontemporal_load(P1 + idx);
    v += __builtin_nontemporal_load(P2 + idx);
    v += __builtin_nontemporal_load(P3 + idx);
    hl[idx] = v + b2v[idx & 31];
  }
  __syncthreads();
  const int r0 = (t >> 5) * 8;
  const int c0 = (t & 31) * 4;
  float acc2[8][4] = {};
  float accR[8][4] = {};
  for (int k = 0; k < 128; k += 4) {
    f32x4 w4v[4], rwv[4];
#pragma unroll
    for (int kk = 0; kk < 4; ++kk) w4v[kk] = *(const f32x4*)(W4 + (k + kk) * 128 + c0);
#pragma unroll
    for (int j = 0; j < 4; ++j) rwv[j] = *(const f32x4*)(res_w + (c0 + j) * 128 + k);
#pragma unroll
    for (int i = 0; i < 8; ++i) {
      f32x4 xv = *(const f32x4*)(hs + (r0 + i) * 128 + k);
#pragma unroll
      for (int kk = 0; kk < 4; ++kk)
#pragma unroll
        for (int j = 0; j < 4; ++j) {
          acc2[i][j] += xv[kk] * w4v[kk][j];
          accR[i][j] += xv[kk] * rwv[j][kk];
        }
    }
  }
  const long R8 = (rowbase + r0) >> 3;
#pragma unroll
  for (int j = 0; j < 4; ++j) {
    u16x8 v;
#pragma unroll
    for (int i = 0; i < 8; ++i) v[i] = f2bf(acc2[i][j]);
    *(u16x8*)(B2 + (R8 * 128 + (c0 + j)) * 8) = v;
  }
  const f32x4 b4v = *(const f32x4*)(b4 + c0);
  const f32x4 rbv = *(const f32x4*)(res_b + c0);
#pragma unroll
  for (int i = 0; i < 8; ++i) {
    f32x4 rv;
#pragma unroll
    for (int j = 0; j < 4; ++j) rv[j] = accR[i][j];
    rv += b4v + rbv;
    *(f32x4*)(Rr + (rowbase + r0 + i) * 128 + c0) = rv;
  }
}

// ---------------------------------------------------------------------------
// K5: out = sum_s P[s] + R
// ---------------------------------------------------------------------------
__global__ __launch_bounds__(256)
void k5_out(const float* __restrict__ P, const float* __restrict__ Rr,
            float* __restrict__ out) {
  const long i = (long)blockIdx.x * 256 + threadIdx.x;   // f32x4 index
  const f32x4* P0 = (const f32x4*)P;
  const f32x4* P1 = P0 + (long)MN * 32;
  const f32x4* P2 = P0 + 2L * MN * 32;
  const f32x4* P3 = P0 + 3L * MN * 32;
  f32x4 v = __builtin_nontemporal_load(P0 + i);
  v += __builtin_nontemporal_load(P1 + i);
  v += __builtin_nontemporal_load(P2 + i);
  v += __builtin_nontemporal_load(P3 + i);
  v += *((const f32x4*)Rr + i);
  __builtin_nontemporal_store(v, (f32x4*)out + i);
}

extern "C" void kernel_launch(void* const* d_in, const int* in_sizes, int n_in,
                              void* d_out, int out_size, void* d_ws, size_t ws_size,
                              hipStream_t stream) {
  const float* x     = (const float*)d_in[0];
  const float* adj   = (const float*)d_in[1];
  const float* W2    = (const float*)d_in[2];
  const float* b2    = (const float*)d_in[3];
  const float* W4    = (const float*)d_in[4];
  const float* b4    = (const float*)d_in[5];
  const float* res_w = (const float*)d_in[6];
  const float* res_b = (const float*)d_in[7];
  float* out = (float*)d_out;

  char* ws = (char*)d_ws;
  u16*   B1 = (u16*)ws;                     // 4 MB  bf16-frag support1
  u16*   B2 = (u16*)(ws + (4L << 20));      // 4 MB  bf16-frag support2
  float* Rr = (float*)(ws + (8L << 20));    // 8 MB  residual + biases
  float* P  = (float*)(ws + (16L << 20));   // 32 MB split-K partials (reused)

  k1_xw2<<<dim3(256), dim3(256), 0, stream>>>(x, W2, B1);
  big_mm<<<dim3(128 * SPLITS), dim3(512), 0, stream>>>(adj, B1, P);
  k3_mid<<<dim3(256), dim3(256), 0, stream>>>(P, b2, W4, res_w, b4, res_b, B2, Rr);
  big_mm<<<dim3(128 * SPLITS), dim3(512), 0, stream>>>(adj, B2, P);
  k5_out<<<dim3(2048), dim3(256), 0, stream>>>(P, Rr, out);
}